// Round 4
// baseline (1026.529 us; speedup 1.0000x reference)
//
#include <hip/hip_runtime.h>
#include <hip/hip_bf16.h>
#include <cstdint>

#define BATCH   4096
#define IN_DIM  1024
#define OUT_DIM 1024
#define NEXP    16

typedef __bf16 bf16;
typedef __attribute__((ext_vector_type(8)))  __bf16 bf16x8;
typedef __attribute__((ext_vector_type(4)))  float  f32x4;
typedef __attribute__((ext_vector_type(16))) float  f32x16;

#define AS1 __attribute__((address_space(1)))
#define AS3 __attribute__((address_space(3)))

__device__ __forceinline__ void gld_lds16(const bf16* g, bf16* l) {
    __builtin_amdgcn_global_load_lds((const AS1 void*)g, (AS3 void*)l, 16, 0, 0);
}

// ---------------------------------------------------------------------------
// Pre-kernel, fused. NO LDS transpose — register transpose only.
// Blocks 0..2047 (W): each handles 2 tiles (2 ne) of wt2. wt2 tile index
//   (oblk*16 + ks)*16 + ne, 8 KB, fragment-ordered for mfma_32x32x16 A-op:
//   chunk c = (kk*2+wm)*64 + l, elem j = W[ne*1024+ks*64+kk*16+(l>>5)*8+j]
//   [oblk*64+wm*32+(l&31)]. Thread loads 8 rows x f32x4 (coalesced 256 B per
//   16 lanes), emits 4 bf16x8 chunks (64 B contiguous per thread).
// Blocks 2048..2303 (x): tile (bblk*16+ks) = 256 b x 64 k = 32 KB, XOR-
//   swizzled row-major; x rows are k-contiguous so no transpose at all.
// ---------------------------------------------------------------------------
__global__ void pre_convert(const float* __restrict__ x, const float* __restrict__ W,
                            bf16* __restrict__ xt, bf16* __restrict__ wt2) {
    int t = threadIdx.x;
    if (blockIdx.x < 2048) {
        int wb2 = blockIdx.x;
        int oblk = wb2 >> 7, ks = (wb2 >> 3) & 15, nepair = wb2 & 7;
        int h = t >> 7, tid7 = t & 127;
        int ne = nepair * 2 + h;
        int g = tid7 & 7, wm = (tid7 >> 3) & 1, kk = (tid7 >> 4) & 3, lh = tid7 >> 6;
        int kg = ne * 1024 + ks * 64 + kk * 16 + lh * 8;
        int o  = oblk * 64 + wm * 32 + g * 4;
        f32x4 ld[8];
#pragma unroll
        for (int j = 0; j < 8; j++)
            ld[j] = *(const f32x4*)(W + (size_t)(kg + j) * OUT_DIM + o);
        size_t tileidx = (size_t)(oblk * 16 + ks) * 16 + ne;
        bf16* dst = wt2 + tileidx * 4096 + ((size_t)((kk * 2 + wm) * 64 + lh * 32 + g * 4)) * 8;
#pragma unroll
        for (int i = 0; i < 4; i++) {
            bf16x8 v;
#pragma unroll
            for (int j = 0; j < 8; j++) v[j] = (bf16)ld[j][i];
            *(bf16x8*)(dst + i * 8) = v;
        }
    } else {
        int xb = blockIdx.x - 2048;
        int bblk = xb >> 4, ks = xb & 15;
#pragma unroll
        for (int r = 0; r < 8; r++) {
            int q = r * 256 + t;               // 2048 chunks of 8 elems
            int b_loc = q >> 3, sc = q & 7;
            int ck = sc ^ (b_loc & 7);
            const float* src = x + (size_t)(bblk * 256 + b_loc) * IN_DIM + ks * 64 + ck * 8;
            f32x4 a = *(const f32x4*)src;
            f32x4 b = *(const f32x4*)(src + 4);
            bf16x8 v;
#pragma unroll
            for (int j = 0; j < 4; j++) { v[j] = (bf16)a[j]; v[4 + j] = (bf16)b[j]; }
            *(bf16x8*)(xt + (size_t)xb * 16384 + q * 8) = v;
        }
    }
}

// ---------------------------------------------------------------------------
// Transposed GEMM, mfma_32x32x16: D[o,b] = relu(Σ_ne cw[b,ne]·(W_ne^T x^T) + bias-term).
// Block 64o x 256b, 512 thr = 8 waves (wm 0..1 over o, wb 0..3 over b),
// wave tile 32o x 64b -> 2 accs (bt). 1 block/CU (96 KB LDS).
// ks outer: x frags -> regs (reused over 16 experts). Experts in chunks of 4:
// W chunk (32 KB) double-buffered, staged one chunk ahead; 4 barriers per ks,
// each covering ~2000 cyc of MFMA. Scales live in 32 VGPRs. Per-expert
// partials folded in fp32 (VALU hides under MFMA, separate pipes).
// ---------------------------------------------------------------------------
__global__ __launch_bounds__(512, 1) void moe_gemm32(
        const float* __restrict__ cw, const float* __restrict__ bias,
        const bf16* __restrict__ xt, const bf16* __restrict__ wt2,
        float* __restrict__ out) {
    int bblk = blockIdx.x;                 // 16
    int oblk = blockIdx.y;                 // 16
    int b0 = bblk * 256, o0 = oblk * 64;
    int t = threadIdx.x;
    int lane = t & 63, w = t >> 6;
    int wm = w & 1, wb = w >> 1;
    int l31 = lane & 31, lh = lane >> 5;

    __shared__ bf16 Wb[2][4 * 4096];       // 2 x 32 KB, 4-expert chunks
    __shared__ bf16 Xb[16384];             // 32 KB x-tile

    // cw scales -> registers (lane's two b columns, all 16 experts)
    f32x4 scf[2][4];
#pragma unroll
    for (int bt = 0; bt < 2; bt++) {
        int b = b0 + wb * 64 + bt * 32 + l31;
#pragma unroll
        for (int i = 0; i < 4; i++)
            scf[bt][i] = *(const f32x4*)(cw + (size_t)b * NEXP + i * 4);
    }

    f32x16 acc[2];
#pragma unroll
    for (int bt = 0; bt < 2; bt++)
#pragma unroll
        for (int i = 0; i < 16; i++) acc[bt][i] = 0.f;
    f32x16 fz16;
#pragma unroll
    for (int i = 0; i < 16; i++) fz16[i] = 0.f;

    const bf16* wsrc = wt2 + (size_t)(oblk * 256) * 4096;   // tiles (ks*16+ne)
    const bf16* xsrc = xt + (size_t)(bblk * 16) * 16384;

    // prologue: stage X(ks=0) and W chunk (ks=0, ne 0..3)
#pragma unroll
    for (int r = 0; r < 4; r++)
        gld_lds16(xsrc + r * 4096 + t * 8, &Xb[r * 4096 + t * 8]);
#pragma unroll
    for (int r = 0; r < 4; r++)
        gld_lds16(wsrc + (size_t)r * 4096 + t * 8, &Wb[0][r * 4096 + t * 8]);
    __syncthreads();

    for (int ks = 0; ks < 16; ks++) {
        // x fragments -> registers (B-operand: n=b=l31, k=lh*8+j within kk*16)
        bf16x8 xf[2][4];
#pragma unroll
        for (int bt = 0; bt < 2; bt++) {
            int b_loc = wb * 64 + bt * 32 + l31;
#pragma unroll
            for (int kk = 0; kk < 4; kk++) {
                int ck = (kk * 2 + lh) ^ (b_loc & 7);
                xf[bt][kk] = *(const bf16x8*)&Xb[b_loc * 64 + ck * 8];
            }
        }
#pragma unroll
        for (int g = 0; g < 4; g++) {
            // stage next W chunk (double-buffer), and next x tile during g==1
            if (g < 3) {
                const bf16* src = wsrc + ((size_t)ks * 16 + (g + 1) * 4) * 4096 + t * 8;
#pragma unroll
                for (int r = 0; r < 4; r++)
                    gld_lds16(src + (size_t)r * 4096, &Wb[(g + 1) & 1][r * 4096 + t * 8]);
            } else if (ks < 15) {
                const bf16* src = wsrc + ((size_t)(ks + 1) * 16) * 4096 + t * 8;
#pragma unroll
                for (int r = 0; r < 4; r++)
                    gld_lds16(src + (size_t)r * 4096, &Wb[0][r * 4096 + t * 8]);
            }
            if (g == 1 && ks < 15) {
                const bf16* src = xsrc + (size_t)(ks + 1) * 16384 + t * 8;
#pragma unroll
                for (int r = 0; r < 4; r++)
                    gld_lds16(src + r * 4096, &Xb[r * 4096 + t * 8]);
            }
            const bf16* wbuf = &Wb[g & 1][0];
#pragma unroll
            for (int nl = 0; nl < 4; nl++) {
                bf16x8 wf[4];
#pragma unroll
                for (int kk = 0; kk < 4; kk++)
                    wf[kk] = *(const bf16x8*)
                        &wbuf[nl * 4096 + ((kk * 2 + wm) * 64 + lane) * 8];
#pragma unroll
                for (int bt = 0; bt < 2; bt++) {
                    f32x16 p = __builtin_amdgcn_mfma_f32_32x32x16_bf16(
                        wf[0], xf[bt][0], fz16, 0, 0, 0);
                    p = __builtin_amdgcn_mfma_f32_32x32x16_bf16(wf[1], xf[bt][1], p, 0, 0, 0);
                    p = __builtin_amdgcn_mfma_f32_32x32x16_bf16(wf[2], xf[bt][2], p, 0, 0, 0);
                    p = __builtin_amdgcn_mfma_f32_32x32x16_bf16(wf[3], xf[bt][3], p, 0, 0, 0);
                    float s = scf[bt][g][nl];          // expert ne = g*4+nl
#pragma unroll
                    for (int i = 0; i < 16; i++) acc[bt][i] += s * p[i];
                }
            }
            __syncthreads();
        }
    }

    // ---- bias term as one mfma k-step: A[o][ne]=bias[ne][o], B[ne][b]=cw[b][ne]
    {
        bf16x8 bfrag;
        int o_l = o0 + wm * 32 + l31;
#pragma unroll
        for (int j = 0; j < 8; j++)
            bfrag[j] = (bf16)bias[(size_t)(lh * 8 + j) * OUT_DIM + o_l];
#pragma unroll
        for (int bt = 0; bt < 2; bt++) {
            f32x4 lo = lh ? scf[bt][2] : scf[bt][0];
            f32x4 hi = lh ? scf[bt][3] : scf[bt][1];
            bf16x8 cf;
#pragma unroll
            for (int j = 0; j < 4; j++) { cf[j] = (bf16)lo[j]; cf[4 + j] = (bf16)hi[j]; }
            acc[bt] = __builtin_amdgcn_mfma_f32_32x32x16_bf16(bfrag, cf, acc[bt], 0, 0, 0);
        }
    }

    // epilogue: relu + store. C/D 32x32: col=lane&31 (=b), row=(r&3)+8*(r>>2)+4*lh (=o)
#pragma unroll
    for (int bt = 0; bt < 2; bt++) {
        int b = b0 + wb * 64 + bt * 32 + l31;
#pragma unroll
        for (int r4 = 0; r4 < 4; r4++) {
            int o = o0 + wm * 32 + r4 * 8 + lh * 4;
            f32x4 v;
#pragma unroll
            for (int i = 0; i < 4; i++) {
                float val = acc[bt][r4 * 4 + i];
                v[i] = val > 0.f ? val : 0.f;
            }
            *(f32x4*)(out + (size_t)b * OUT_DIM + o) = v;
        }
    }
}

// ---------------------------------------------------------------------------
// Insurance fallback if ws_size is too small.
// ---------------------------------------------------------------------------
__global__ void fallback_kernel(const float* __restrict__ x, const float* __restrict__ cw,
                                const float* __restrict__ W, const float* __restrict__ bias,
                                float* __restrict__ out) {
    int o = blockIdx.x * 256 + threadIdx.x;
    int b = o >> 10, oc = o & 1023;
    const float* xr = x + (size_t)b * IN_DIM;
    float accv = 0.f;
    for (int n = 0; n < NEXP; n++) {
        const float* wr = W + (size_t)n * IN_DIM * OUT_DIM + oc;
        float z = 0.f;
        for (int i = 0; i < IN_DIM; i++) z += xr[i] * wr[(size_t)i * OUT_DIM];
        accv += cw[(size_t)b * NEXP + n] * (z + bias[n * OUT_DIM + oc]);
    }
    out[o] = accv > 0.f ? accv : 0.f;
}

extern "C" void kernel_launch(void* const* d_in, const int* in_sizes, int n_in,
                              void* d_out, int out_size, void* d_ws, size_t ws_size,
                              hipStream_t stream) {
    const float* x    = (const float*)d_in[0];
    const float* cw   = (const float*)d_in[1];
    const float* W    = (const float*)d_in[2];
    const float* bias = (const float*)d_in[3];
    float* out = (float*)d_out;

    const size_t wt_elems = (size_t)NEXP * IN_DIM * OUT_DIM;   // 16.7M bf16
    const size_t xt_elems = (size_t)BATCH * IN_DIM;            // 4.2M bf16
    if (ws_size < (wt_elems + xt_elems) * sizeof(bf16)) {
        fallback_kernel<<<(BATCH * OUT_DIM) / 256, 256, 0, stream>>>(x, cw, W, bias, out);
        return;
    }
    bf16* wt2 = (bf16*)d_ws;
    bf16* xt = wt2 + wt_elems;

    pre_convert<<<2304, 256, 0, stream>>>(x, W, xt, wt2);
    moe_gemm32<<<dim3(16, 16), 512, 0, stream>>>(cw, bias, xt, wt2, out);
}